// Round 5
// baseline (2131.134 us; speedup 1.0000x reference)
//
#include <hip/hip_runtime.h>
#include <math.h>

// Neural Turing Machine forward, fully fused persistent kernel.
// R5: G=1 batch element per block, 512 blocks x 512 threads, LDS ~52 KB
// -> TWO independent blocks per CU (two barrier domains). R2/R4 showed
// 1 block/CU is barrier/latency-serialized (VALUBusy 47%, adding waves to
// the same block did nothing). Per-CU compute unchanged; weight streaming
// doubles (L2 floor ~1.25 ms at 34.5 TB/s) - acceptable, we used ~11 TB/s.

#define NSLOT  256
#define MU     32
#define MPAD   33      // +1 pad: avoids 32-bank conflicts on M rows
#define TSTEPS 64
#define EPSF   1e-8f

__device__ __forceinline__ float sigf(float x){ return 1.0f/(1.0f + expf(-x)); }
__device__ __forceinline__ float softplusf_(float x){ return fmaxf(x,0.0f) + log1pf(expf(-fabsf(x))); }

__device__ __forceinline__ float wred_sum(float v){
  #pragma unroll
  for (int m = 32; m >= 1; m >>= 1) v += __shfl_xor(v, m, 64);
  return v;
}
__device__ __forceinline__ float wred_max(float v){
  #pragma unroll
  for (int m = 32; m >= 1; m >>= 1) v = fmaxf(v, __shfl_xor(v, m, 64));
  return v;
}

struct __align__(16) Smem {
  float M[NSLOT][MPAD];      // memory, padded rows            33.8 KB
  float zp[2][1024];         // z partials [khalf][col]         8   KB
  float h[256];              // 16B-aligned for float4 reads
  float c[256];
  float hob[140];            // [read ho(38) | write wo(102)]
  float pad0;                // keep xcat 16B-aligned (560+4+... )
  float xcat[40];            // [x(8) | R(32)]
  float pad1[3];
  float wr[NSLOT];           // read weights state
  float ww[NSLOT];           // write weights state
  float wg[2][NSLOT];        // shift-conv scratch [head][slot]
  float k[2][MU];            // key buffer [head][m]
  float E[MU];
  float A[MU];
  float R[MU];
  float hpart[2][140];       // head GEMM partials [khalf][col]
  float rpart[16][32];       // read-vector partials [chunk][m]
  float red[3][8];           // per-site reduction buffers (8 waves)
};  // ~52 KB -> 2 blocks/CU (104 KB of 160)

// Reduction over the 256 slot-threads (waves 0-3). Waves 4-7 duplicate the
// same values (same n2) - their red[] slots are written but never read.
// Caller passes a DISTINCT red buffer per site. ALL 512 threads must call.
__device__ __forceinline__ float grp_red_sum(float v, float* red, int wave, int lane){
  v = wred_sum(v);
  if (lane == 0) red[wave] = v;
  __syncthreads();
  return red[0] + red[1] + red[2] + red[3];
}
__device__ __forceinline__ float grp_red_max(float v, float* red, int wave, int lane){
  v = wred_max(v);
  if (lane == 0) red[wave] = v;
  __syncthreads();
  return fmaxf(fmaxf(red[0], red[1]), fmaxf(red[2], red[3]));
}

// NTM addressing for one head. act threads (tid<256) own slot n2; waves 4-7
// duplicate the computation with writes suppressed or benignly identical.
// head = 0 (read) / 1 (write) selects private k/wg buffers.
__device__ void address_head(bool act, int n2, int wave, int lane, int head,
                             const float* ho, float* wst, Smem& s)
{
  // per-head scalars, computed redundantly per thread (LDS broadcast reads)
  float beta  = softplusf_(ho[32]);
  float gg    = sigf(ho[33]);
  float r0 = ho[34], r1 = ho[35], r2 = ho[36];
  float m3 = fmaxf(r0, fmaxf(r1, r2));
  float e0 = expf(r0-m3), e1 = expf(r1-m3), e2 = expf(r2-m3);
  float inv3 = 1.0f/(e0+e1+e2);
  float s0 = e0*inv3, s1 = e1*inv3, s2 = e2*inv3;
  float gamma = 1.0f + softplusf_(ho[37]);

  float* kbuf  = &s.k[head][0];
  float* wgbuf = &s.wg[head][0];

  if (act && n2 < MU) kbuf[n2] = tanhf(ho[n2]);
  __syncthreads();

  float kn = 0.0f;
  #pragma unroll
  for (int m = 0; m < MU; ++m){ float kv = kbuf[m]; kn = fmaf(kv, kv, kn); }
  kn = sqrtf(kn);

  // cosine similarity for this thread's slot n2
  const float* Mr = &s.M[n2][0];
  float dot = 0.0f, mm = 0.0f;
  #pragma unroll
  for (int m = 0; m < MU; ++m){ float mv = Mr[m]; dot = fmaf(mv, kbuf[m], dot); mm = fmaf(mv, mv, mm); }
  float sim = dot / (sqrtf(mm)*kn + EPSF);

  // content softmax over 256 slots
  float bs = beta * sim;
  float mx = grp_red_max(bs, s.red[0], wave, lane);
  float ex = expf(bs - mx);
  float sm = grp_red_sum(ex, s.red[1], wave, lane);
  float wc = ex / sm;

  // interpolate with previous weights, publish for shift conv
  float wgv = fmaf(gg, wc, (1.0f - gg)*wst[n2]);
  if (act) wgbuf[n2] = wgv;
  __syncthreads();

  // circular shift conv: w_s[i] = s0*wg[i+1] + s1*wg[i] + s2*wg[i-1]
  float ws = s0*wgbuf[(n2+1)&255] + s1*wgbuf[n2] + s2*wgbuf[(n2-1)&255];

  // sharpen + normalize
  float wp = powf(ws, gamma);
  float sp = grp_red_sum(wp, s.red[2], wave, lane);
  if (act) wst[n2] = wp / (sp + EPSF);
}

__global__ __launch_bounds__(512, 4)
void ntm_fused(const float* __restrict__ X,
               const float* __restrict__ Wk,   const float* __restrict__ Wr,
               const float* __restrict__ Lb,
               const float* __restrict__ rW,   const float* __restrict__ rb,
               const float* __restrict__ wW,   const float* __restrict__ wb,
               const float* __restrict__ oW,   const float* __restrict__ ob,
               const float* __restrict__ rInit,
               const float* __restrict__ wrI,  const float* __restrict__ wwI,
               float* __restrict__ Y)
{
  __shared__ Smem s;

  const int tid  = threadIdx.x;
  const int q    = tid >> 8;        // k-half 0/1 for the z-GEMM
  const int n2   = tid & 255;       // unit / slot / column-group index
  const int wave = tid >> 6;        // 0..7
  const int lane = tid & 63;
  const bool act = (tid < 256);     // active in 256-wide phases
  const int b    = blockIdx.x;      // this block's batch element

  // ---------------- init state ----------------
  if (act) {
    for (int m = 0; m < MU; ++m) s.M[n2][m] = 1e-6f;
    s.h[n2] = 0.0f;
    s.c[n2] = 0.0f;
    if (n2 < MU) s.R[n2] = tanhf(rInit[n2]);
    // initial weight softmaxes (serial per thread, init-only, broadcast reads)
    float mx = -1e30f;
    for (int i = 0; i < NSLOT; ++i) mx = fmaxf(mx, wrI[i]);
    float sm = 0.0f;
    for (int i = 0; i < NSLOT; ++i) sm += expf(wrI[i] - mx);
    s.wr[n2] = expf(wrI[n2] - mx) / sm;
    mx = -1e30f;
    for (int i = 0; i < NSLOT; ++i) mx = fmaxf(mx, wwI[i]);
    sm = 0.0f;
    for (int i = 0; i < NSLOT; ++i) sm += expf(wwI[i] - mx);
    s.ww[n2] = expf(wwI[n2] - mx) / sm;
  }
  __syncthreads();

  // ---------------- time loop ----------------
  for (int t = 0; t < TSTEPS; ++t) {
    // x_cat = [x(8) | R(32)]
    if (tid < 40) {
      s.xcat[tid] = (tid < 8) ? X[(b*TSTEPS + t)*8 + tid] : s.R[tid - 8];
    }
    __syncthreads();

    // ---- z = x_cat@Wk + h@Wr (+b in gate phase); 2-way k-split ----
    // q0: Wk rows 0..39 + Wr rows 0..107 (37 4-row bodies)
    // q1: Wr rows 108..255 (37 bodies)
    {
      const int c0 = n2 * 4;
      float ax=0.f, ay=0.f, az=0.f, aw=0.f;
      if (q == 0) {
        #pragma unroll 2
        for (int i4 = 0; i4 < 10; ++i4) {
          const int r = i4*4;
          float4 x0 = *(const float4*)&s.xcat[r];
          float4 w0 = *(const float4*)&Wk[(r+0)*1024 + c0];
          float4 w1 = *(const float4*)&Wk[(r+1)*1024 + c0];
          float4 w2 = *(const float4*)&Wk[(r+2)*1024 + c0];
          float4 w3 = *(const float4*)&Wk[(r+3)*1024 + c0];
          ax=fmaf(w0.x,x0.x,ax); ay=fmaf(w0.y,x0.x,ay); az=fmaf(w0.z,x0.x,az); aw=fmaf(w0.w,x0.x,aw);
          ax=fmaf(w1.x,x0.y,ax); ay=fmaf(w1.y,x0.y,ay); az=fmaf(w1.z,x0.y,az); aw=fmaf(w1.w,x0.y,aw);
          ax=fmaf(w2.x,x0.z,ax); ay=fmaf(w2.y,x0.z,ay); az=fmaf(w2.z,x0.z,az); aw=fmaf(w2.w,x0.z,aw);
          ax=fmaf(w3.x,x0.w,ax); ay=fmaf(w3.y,x0.w,ay); az=fmaf(w3.z,x0.w,az); aw=fmaf(w3.w,x0.w,aw);
        }
      }
      const int rlo = (q==0) ? 0   : 108;
      const int rhi = (q==0) ? 108 : 256;
      #pragma unroll 2
      for (int r = rlo; r < rhi; r += 4) {
        float4 h0 = *(const float4*)&s.h[r];
        float4 w0 = *(const float4*)&Wr[(r+0)*1024 + c0];
        float4 w1 = *(const float4*)&Wr[(r+1)*1024 + c0];
        float4 w2 = *(const float4*)&Wr[(r+2)*1024 + c0];
        float4 w3 = *(const float4*)&Wr[(r+3)*1024 + c0];
        ax=fmaf(w0.x,h0.x,ax); ay=fmaf(w0.y,h0.x,ay); az=fmaf(w0.z,h0.x,az); aw=fmaf(w0.w,h0.x,aw);
        ax=fmaf(w1.x,h0.y,ax); ay=fmaf(w1.y,h0.y,ay); az=fmaf(w1.z,h0.y,az); aw=fmaf(w1.w,h0.y,aw);
        ax=fmaf(w2.x,h0.z,ax); ay=fmaf(w2.y,h0.z,ay); az=fmaf(w2.z,h0.z,az); aw=fmaf(w2.w,h0.z,aw);
        ax=fmaf(w3.x,h0.w,ax); ay=fmaf(w3.y,h0.w,ay); az=fmaf(w3.z,h0.w,az); aw=fmaf(w3.w,h0.w,aw);
      }
      *(float4*)&s.zp[q][c0] = make_float4(ax,ay,az,aw);
    }
    __syncthreads();

    // ---- LSTM gates (keras order i,f,g,o); Z==h since |h|<1<CLIP ----
    if (act) {
      float zi = s.zp[0][n2      ] + s.zp[1][n2      ] + Lb[n2      ];
      float zf = s.zp[0][n2 + 256] + s.zp[1][n2 + 256] + Lb[n2 + 256];
      float zg = s.zp[0][n2 + 512] + s.zp[1][n2 + 512] + Lb[n2 + 512];
      float zo = s.zp[0][n2 + 768] + s.zp[1][n2 + 768] + Lb[n2 + 768];
      float cn = sigf(zf)*s.c[n2] + sigf(zi)*tanhf(zg);
      float hn = sigf(zo)*tanhf(cn);
      s.c[n2] = cn;
      s.h[n2] = hn;
    }
    __syncthreads();

    // ---- head outputs: ho = h @ [read_W | write_W]; 2-way k-split ----
    // item = (k-half q2, col cc): 280 of 512 threads active
    if (tid < 280) {
      const int q2 = tid / 140;
      const int cc = tid % 140;
      const float* Wp; int stride, c;
      if (cc < 38) { Wp = rW; stride = 38;  c = cc; }
      else         { Wp = wW; stride = 102; c = cc - 38; }
      const int i0 = q2 * 128;
      float acc = 0.0f;
      #pragma unroll 2
      for (int r4 = 0; r4 < 32; ++r4) {
        const int r = i0 + r4*4;
        float4 h0 = *(const float4*)&s.h[r];
        float wv0 = Wp[(r+0)*stride + c];
        float wv1 = Wp[(r+1)*stride + c];
        float wv2 = Wp[(r+2)*stride + c];
        float wv3 = Wp[(r+3)*stride + c];
        acc = fmaf(wv0, h0.x, acc);
        acc = fmaf(wv1, h0.y, acc);
        acc = fmaf(wv2, h0.z, acc);
        acc = fmaf(wv3, h0.w, acc);
      }
      s.hpart[q2][cc] = acc;
    }
    __syncthreads();
    if (tid < 140) {
      float bias = (tid < 38) ? rb[tid] : wb[tid - 38];
      s.hob[tid] = s.hpart[0][tid] + s.hpart[1][tid] + bias;
    }
    __syncthreads();

    // erase / add vectors (write head raw outputs wo[38:70], wo[70:102])
    if (tid < MU) {
      s.E[tid] = sigf(s.hob[76 + tid]);
      s.A[tid] = tanhf(s.hob[108 + tid]);
    }

    // ---- read head addressing (pre-write M), then write head addressing ----
    address_head(act, n2, wave, lane, 0, &s.hob[0],  &s.wr[0], s);
    address_head(act, n2, wave, lane, 1, &s.hob[38], &s.ww[0], s);

    // ---- R = wr . M (pre-write M); 512 threads, 16 chunks x 16 slots ----
    {
      const int chunk = tid >> 5;      // 0..15
      const int m     = tid & 31;
      const int nb = chunk * 16;
      float acc = 0.0f;
      #pragma unroll 4
      for (int nn = 0; nn < 16; ++nn) {
        const int n = nb + nn;
        acc = fmaf(s.wr[n], s.M[n][m], acc);
      }
      s.rpart[chunk][m] = acc;
    }
    __syncthreads();
    if (tid < MU) {
      float r = 0.0f;
      #pragma unroll
      for (int c = 0; c < 16; ++c) r += s.rpart[c][tid];
      s.R[tid] = r;
    }
    __syncthreads();

    // ---- memory write: M = M*(1 - ww*E) + ww*A; 512 threads, half-row each ----
    {
      const int row  = tid >> 1;
      const int half = tid & 1;
      const float wwn = s.ww[row];
      float* Mr       = &s.M[row][half*16];
      const float* Eg = &s.E[half*16];
      const float* Ag = &s.A[half*16];
      #pragma unroll
      for (int m = 0; m < 16; ++m) {
        Mr[m] = Mr[m] * (1.0f - wwn*Eg[m]) + wwn*Ag[m];
      }
    }

    // ---- output: Y = clip([R | h] @ out_W + b) ----
    if (act) {
      const int o = n2 >> 5;   // 0..7
      const int l = n2 & 31;
      float acc = 0.0f;
      #pragma unroll
      for (int ss = 0; ss < 9; ++ss) {
        const int j = l + 32*ss;     // covers 0..287 exactly
        float v = (j < 32) ? s.R[j] : s.h[j - 32];
        acc = fmaf(v, oW[j*8 + o], acc);
      }
      #pragma unroll
      for (int m = 16; m >= 1; m >>= 1) acc += __shfl_xor(acc, m, 64);
      if (l == 0) {
        float y = acc + ob[o];
        y = fminf(fmaxf(y, -20.0f), 20.0f);
        Y[(b*TSTEPS + t)*8 + o] = y;
      }
    }
    __syncthreads();
  }
}

extern "C" void kernel_launch(void* const* d_in, const int* in_sizes, int n_in,
                              void* d_out, int out_size, void* d_ws, size_t ws_size,
                              hipStream_t stream)
{
  const float* X     = (const float*)d_in[0];
  const float* Wk    = (const float*)d_in[1];
  const float* Wr    = (const float*)d_in[2];
  const float* Lb    = (const float*)d_in[3];
  const float* rW    = (const float*)d_in[4];
  const float* rb    = (const float*)d_in[5];
  const float* wW    = (const float*)d_in[6];
  const float* wb    = (const float*)d_in[7];
  const float* oW    = (const float*)d_in[8];
  const float* ob    = (const float*)d_in[9];
  const float* rInit = (const float*)d_in[10];
  const float* wrI   = (const float*)d_in[11];
  const float* wwI   = (const float*)d_in[12];
  float* Y = (float*)d_out;

  hipLaunchKernelGGL(ntm_fused, dim3(512), dim3(512), 0, stream,
                     X, Wk, Wr, Lb, rW, rb, wW, wb, oW, ob, rInit, wrI, wwI, Y);
}

// Round 9
// 1542.543 us; speedup vs baseline: 1.3816x; 1.3816x over previous
//
#include <hip/hip_runtime.h>
#include <math.h>

// Neural Turing Machine forward, fully fused persistent kernel.
// R9 = R6 resubmitted verbatim (three consecutive GPU-acquisition failures;
// kernel never measured). Rationale:
//  - best topology (R2): 256 blocks x 512 threads, G=2 batch elems/block,
//    1 block/CU, weights streamed once per CU-step
//  - fused read+write head addressing (shared M-row reads and ||M||,
//    paired reductions): 5 barriers instead of 10, ~half the LDS traffic
//  - float4 z-GEMM; no launch_bounds min-wave arg (R3/R5: forces VGPR=64)
//  - 12 barriers/step total (was ~18)
// Numerics identical to the passing R2/R4 kernels (tanhf/expf/powf).

#define NSLOT  256
#define MU     32
#define MPAD   33      // +1 pad: M row scalar reads are 2-way/bank = free
#define TSTEPS 64
#define EPSF   1e-8f

__device__ __forceinline__ float sigf(float x){ return 1.0f/(1.0f + expf(-x)); }
__device__ __forceinline__ float softplusf_(float x){ return fmaxf(x,0.0f) + log1pf(expf(-fabsf(x))); }

// paired 64-lane butterfly reductions (two independent values per lane)
__device__ __forceinline__ void wred_sum2(float& a, float& b){
  #pragma unroll
  for (int m = 32; m >= 1; m >>= 1){ a += __shfl_xor(a, m, 64); b += __shfl_xor(b, m, 64); }
}
__device__ __forceinline__ void wred_max2(float& a, float& b){
  #pragma unroll
  for (int m = 32; m >= 1; m >>= 1){ a = fmaxf(a, __shfl_xor(a, m, 64)); b = fmaxf(b, __shfl_xor(b, m, 64)); }
}

struct __align__(16) Smem {
  float M[2][NSLOT][MPAD];   // 67.6 KB, padded rows
  float zp[2][2][1024];      // z partials [khalf][g][col], 16 KB
  float h[2][256];           // 16B-aligned (offset mult of 16)
  float c[2][256];
  float hob[2][140];         // [read ho(38) | write wo(102)]
  float xcat[2][40];         // [x(8) | R(32)]  (16B-aligned)
  float wr[2][NSLOT];        // read weights state
  float ww[2][NSLOT];        // write weights state
  float wg[2][2][NSLOT];     // gated weights scratch [head][g][slot]
  float k[2][2][MU];         // keys [head][g][m]
  float kn2[2][2];           // key norms [head][g]
  float E[2][MU];
  float A[2][MU];
  float R[2][MU];
  float rpart[2][8][MU];     // read-vector partials [g][chunk][m]
  float red[4][8];           // paired reduction slots [site][wave]
};  // ~103 KB -> 1 block/CU

__global__ __launch_bounds__(512)
void ntm_fused(const float* __restrict__ X,
               const float* __restrict__ Wk,   const float* __restrict__ Wr,
               const float* __restrict__ Lb,
               const float* __restrict__ rW,   const float* __restrict__ rb,
               const float* __restrict__ wW,   const float* __restrict__ wb,
               const float* __restrict__ oW,   const float* __restrict__ ob,
               const float* __restrict__ rInit,
               const float* __restrict__ wrI,  const float* __restrict__ wwI,
               float* __restrict__ Y)
{
  __shared__ Smem s;

  const int tid  = threadIdx.x;
  const int q    = tid >> 8;        // k-half for z-GEMM
  const int n2   = tid & 255;       // col-group / unit / slot index
  const int g2   = tid >> 8;        // batch slot for per-element phases
  const int wave = tid >> 6;        // 0..7
  const int lane = tid & 63;
  const int wb0  = g2 * 4;          // first wave of this element's group
  const int bB   = blockIdx.x * 2;  // first batch element of this block

  // ---------------- init state ----------------
  {
    for (int m = 0; m < MU; ++m) s.M[g2][n2][m] = 1e-6f;
    s.h[g2][n2] = 0.0f;
    s.c[g2][n2] = 0.0f;
    if (n2 < MU) s.R[g2][n2] = tanhf(rInit[n2]);
    if (n2 < 40)
      s.xcat[g2][n2] = (n2 < 8) ? X[((bB + g2)*TSTEPS + 0)*8 + n2]
                                : tanhf(rInit[n2 - 8]);
    // initial weight softmaxes (once; serial per thread, broadcast reads)
    float mx = -1e30f;
    for (int i = 0; i < NSLOT; ++i) mx = fmaxf(mx, wrI[i]);
    float sm = 0.0f;
    for (int i = 0; i < NSLOT; ++i) sm += expf(wrI[i] - mx);
    s.wr[g2][n2] = expf(wrI[n2] - mx) / sm;
    mx = -1e30f;
    for (int i = 0; i < NSLOT; ++i) mx = fmaxf(mx, wwI[i]);
    sm = 0.0f;
    for (int i = 0; i < NSLOT; ++i) sm += expf(wwI[i] - mx);
    s.ww[g2][n2] = expf(wwI[n2] - mx) / sm;
  }
  __syncthreads();

  // ---------------- time loop (12 barriers/step) ----------------
  for (int t = 0; t < TSTEPS; ++t) {
    // ---- P1: z = xcat@Wk + h@Wr; 2-way k-split, float4, both elems ----
    // q0: Wk rows 0..39 + Wr rows 0..107; q1: Wr rows 108..255.
    {
      const int c0 = n2 * 4;
      float a0x=0.f,a0y=0.f,a0z=0.f,a0w=0.f;   // g=0
      float a1x=0.f,a1y=0.f,a1z=0.f,a1w=0.f;   // g=1
      if (q == 0) {
        #pragma unroll 2
        for (int i4 = 0; i4 < 10; ++i4) {
          const int r = i4*4;
          float4 x0 = *(const float4*)&s.xcat[0][r];
          float4 x1 = *(const float4*)&s.xcat[1][r];
          float4 w0 = *(const float4*)&Wk[(r+0)*1024 + c0];
          float4 w1 = *(const float4*)&Wk[(r+1)*1024 + c0];
          float4 w2 = *(const float4*)&Wk[(r+2)*1024 + c0];
          float4 w3 = *(const float4*)&Wk[(r+3)*1024 + c0];
          a0x=fmaf(w0.x,x0.x,a0x); a0y=fmaf(w0.y,x0.x,a0y); a0z=fmaf(w0.z,x0.x,a0z); a0w=fmaf(w0.w,x0.x,a0w);
          a1x=fmaf(w0.x,x1.x,a1x); a1y=fmaf(w0.y,x1.x,a1y); a1z=fmaf(w0.z,x1.x,a1z); a1w=fmaf(w0.w,x1.x,a1w);
          a0x=fmaf(w1.x,x0.y,a0x); a0y=fmaf(w1.y,x0.y,a0y); a0z=fmaf(w1.z,x0.y,a0z); a0w=fmaf(w1.w,x0.y,a0w);
          a1x=fmaf(w1.x,x1.y,a1x); a1y=fmaf(w1.y,x1.y,a1y); a1z=fmaf(w1.z,x1.y,a1z); a1w=fmaf(w1.w,x1.y,a1w);
          a0x=fmaf(w2.x,x0.z,a0x); a0y=fmaf(w2.y,x0.z,a0y); a0z=fmaf(w2.z,x0.z,a0z); a0w=fmaf(w2.w,x0.z,a0w);
          a1x=fmaf(w2.x,x1.z,a1x); a1y=fmaf(w2.y,x1.z,a1y); a1z=fmaf(w2.z,x1.z,a1z); a1w=fmaf(w2.w,x1.z,a1w);
          a0x=fmaf(w3.x,x0.w,a0x); a0y=fmaf(w3.y,x0.w,a0y); a0z=fmaf(w3.z,x0.w,a0z); a0w=fmaf(w3.w,x0.w,a0w);
          a1x=fmaf(w3.x,x1.w,a1x); a1y=fmaf(w3.y,x1.w,a1y); a1z=fmaf(w3.z,x1.w,a1z); a1w=fmaf(w3.w,x1.w,a1w);
        }
      }
      const int rlo = (q==0) ? 0   : 108;
      const int rhi = (q==0) ? 108 : 256;
      #pragma unroll 2
      for (int r = rlo; r < rhi; r += 4) {
        float4 h0 = *(const float4*)&s.h[0][r];
        float4 h1 = *(const float4*)&s.h[1][r];
        float4 w0 = *(const float4*)&Wr[(r+0)*1024 + c0];
        float4 w1 = *(const float4*)&Wr[(r+1)*1024 + c0];
        float4 w2 = *(const float4*)&Wr[(r+2)*1024 + c0];
        float4 w3 = *(const float4*)&Wr[(r+3)*1024 + c0];
        a0x=fmaf(w0.x,h0.x,a0x); a0y=fmaf(w0.y,h0.x,a0y); a0z=fmaf(w0.z,h0.x,a0z); a0w=fmaf(w0.w,h0.x,a0w);
        a1x=fmaf(w0.x,h1.x,a1x); a1y=fmaf(w0.y,h1.x,a1y); a1z=fmaf(w0.z,h1.x,a1z); a1w=fmaf(w0.w,h1.x,a1w);
        a0x=fmaf(w1.x,h0.y,a0x); a0y=fmaf(w1.y,h0.y,a0y); a0z=fmaf(w1.z,h0.y,a0z); a0w=fmaf(w1.w,h0.y,a0w);
        a1x=fmaf(w1.x,h1.y,a1x); a1y=fmaf(w1.y,h1.y,a1y); a1z=fmaf(w1.z,h1.y,a1z); a1w=fmaf(w1.w,h1.y,a1w);
        a0x=fmaf(w2.x,h0.z,a0x); a0y=fmaf(w2.y,h0.z,a0y); a0z=fmaf(w2.z,h0.z,a0z); a0w=fmaf(w2.w,h0.z,a0w);
        a1x=fmaf(w2.x,h1.z,a1x); a1y=fmaf(w2.y,h1.z,a1y); a1z=fmaf(w2.z,h1.z,a1z); a1w=fmaf(w2.w,h1.z,a1w);
        a0x=fmaf(w3.x,h0.w,a0x); a0y=fmaf(w3.y,h0.w,a0y); a0z=fmaf(w3.z,h0.w,a0z); a0w=fmaf(w3.w,h0.w,a0w);
        a1x=fmaf(w3.x,h1.w,a1x); a1y=fmaf(w3.y,h1.w,a1y); a1z=fmaf(w3.z,h1.w,a1z); a1w=fmaf(w3.w,h1.w,a1w);
      }
      *(float4*)&s.zp[q][0][c0] = make_float4(a0x,a0y,a0z,a0w);
      *(float4*)&s.zp[q][1][c0] = make_float4(a1x,a1y,a1z,a1w);
    }
    __syncthreads();                                   // bar 1

    // ---- P2: LSTM gates (keras i,f,g,o); Z==h since |h|<1<CLIP ----
    {
      float zi = s.zp[0][g2][n2      ] + s.zp[1][g2][n2      ] + Lb[n2      ];
      float zf = s.zp[0][g2][n2 + 256] + s.zp[1][g2][n2 + 256] + Lb[n2 + 256];
      float zg = s.zp[0][g2][n2 + 512] + s.zp[1][g2][n2 + 512] + Lb[n2 + 512];
      float zo = s.zp[0][g2][n2 + 768] + s.zp[1][g2][n2 + 768] + Lb[n2 + 768];
      float cn = sigf(zf)*s.c[g2][n2] + sigf(zi)*tanhf(zg);
      float hn = sigf(zo)*tanhf(cn);
      s.c[g2][n2] = cn;
      s.h[g2][n2] = hn;
    }
    __syncthreads();                                   // bar 2

    // ---- P3: head outputs ho = h @ [read_W | write_W] + bias, full dot ----
    if (tid < 280) {
      const int g  = tid / 140;
      const int cc = tid % 140;
      const float* Wp; int stride, c; float acc;
      if (cc < 38) { Wp = rW; stride = 38;  c = cc;      acc = rb[c]; }
      else         { Wp = wW; stride = 102; c = cc - 38; acc = wb[c]; }
      #pragma unroll 4
      for (int r4 = 0; r4 < 64; ++r4) {
        const int r = r4*4;
        float4 hv = *(const float4*)&s.h[g][r];
        acc = fmaf(Wp[(r+0)*stride + c], hv.x, acc);
        acc = fmaf(Wp[(r+1)*stride + c], hv.y, acc);
        acc = fmaf(Wp[(r+2)*stride + c], hv.z, acc);
        acc = fmaf(Wp[(r+3)*stride + c], hv.w, acc);
      }
      s.hob[g][cc] = acc;
    }
    __syncthreads();                                   // bar 3

    // ---- P4: keys + key norms (in-wave) + E/A vectors ----
    if (n2 < 64) {
      const int half = n2 >> 5;           // 0: read key, 1: write key
      const int m    = n2 & 31;
      float kv = tanhf(s.hob[g2][half*38 + m]);
      s.k[half][g2][m] = kv;
      float p = kv*kv;
      #pragma unroll
      for (int mm_ = 16; mm_ >= 1; mm_ >>= 1) p += __shfl_xor(p, mm_, 64);
      if (m == 0) s.kn2[half][g2] = sqrtf(p);
    } else if (n2 < 96) {
      const int m = n2 & 31;
      s.E[g2][m] = sigf(s.hob[g2][76 + m]);
    } else if (n2 < 128) {
      const int m = n2 & 31;
      s.A[g2][m] = tanhf(s.hob[g2][108 + m]);
    }
    __syncthreads();                                   // bar 4

    // ---- P5: fused cosine sims (shared M row+norm) + paired max-reduce ----
    float bsr, bsw, exr, exw;
    {
      const float* Mr = &s.M[g2][n2][0];
      const float* kr = &s.k[0][g2][0];
      const float* kw = &s.k[1][g2][0];
      float dr = 0.f, dw = 0.f, mm = 0.f;
      #pragma unroll
      for (int m = 0; m < MU; ++m) {
        float Mv = Mr[m];
        dr = fmaf(Mv, kr[m], dr);
        dw = fmaf(Mv, kw[m], dw);
        mm = fmaf(Mv, Mv, mm);
      }
      float nM = sqrtf(mm);
      float simr = dr / (nM * s.kn2[0][g2] + EPSF);
      float simw = dw / (nM * s.kn2[1][g2] + EPSF);
      bsr = softplusf_(s.hob[g2][32])      * simr;
      bsw = softplusf_(s.hob[g2][38 + 32]) * simw;
      float mr = bsr, mw = bsw;
      wred_max2(mr, mw);
      if (lane == 0) { s.red[0][wave] = mr; s.red[1][wave] = mw; }
    }
    __syncthreads();                                   // bar 5

    // ---- P6: softmax exp + paired sum-reduce ----
    {
      float mxr = fmaxf(fmaxf(s.red[0][wb0], s.red[0][wb0+1]), fmaxf(s.red[0][wb0+2], s.red[0][wb0+3]));
      float mxw = fmaxf(fmaxf(s.red[1][wb0], s.red[1][wb0+1]), fmaxf(s.red[1][wb0+2], s.red[1][wb0+3]));
      exr = expf(bsr - mxr);
      exw = expf(bsw - mxw);
      float sr = exr, sw = exw;
      wred_sum2(sr, sw);
      if (lane == 0) { s.red[2][wave] = sr; s.red[3][wave] = sw; }
    }
    __syncthreads();                                   // bar 6

    // ---- P7: content weights + interpolation, publish for shift conv ----
    {
      float smr = s.red[2][wb0] + s.red[2][wb0+1] + s.red[2][wb0+2] + s.red[2][wb0+3];
      float smw = s.red[3][wb0] + s.red[3][wb0+1] + s.red[3][wb0+2] + s.red[3][wb0+3];
      float wcr = exr / smr;
      float wcw = exw / smw;
      float ggr = sigf(s.hob[g2][33]);
      float ggw = sigf(s.hob[g2][38 + 33]);
      s.wg[0][g2][n2] = fmaf(ggr, wcr, (1.0f - ggr) * s.wr[g2][n2]);
      s.wg[1][g2][n2] = fmaf(ggw, wcw, (1.0f - ggw) * s.ww[g2][n2]);
    }
    __syncthreads();                                   // bar 7

    // ---- P8: shift conv + sharpen + paired sum-reduce ----
    float wpr, wpw;
    {
      float r0 = s.hob[g2][34], r1 = s.hob[g2][35], r2 = s.hob[g2][36];
      float m3 = fmaxf(r0, fmaxf(r1, r2));
      float e0 = expf(r0-m3), e1 = expf(r1-m3), e2 = expf(r2-m3);
      float iv = 1.0f/(e0+e1+e2);
      float s0r = e0*iv, s1r = e1*iv, s2r = e2*iv;
      float gmr = 1.0f + softplusf_(s.hob[g2][37]);
      r0 = s.hob[g2][38+34]; r1 = s.hob[g2][38+35]; r2 = s.hob[g2][38+36];
      m3 = fmaxf(r0, fmaxf(r1, r2));
      e0 = expf(r0-m3); e1 = expf(r1-m3); e2 = expf(r2-m3);
      iv = 1.0f/(e0+e1+e2);
      float s0w = e0*iv, s1w = e1*iv, s2w = e2*iv;
      float gmw = 1.0f + softplusf_(s.hob[g2][38+37]);

      const int np = (n2+1) & 255, nm = (n2-1) & 255;
      float wsr = s0r*s.wg[0][g2][np] + s1r*s.wg[0][g2][n2] + s2r*s.wg[0][g2][nm];
      float wsw = s0w*s.wg[1][g2][np] + s1w*s.wg[1][g2][n2] + s2w*s.wg[1][g2][nm];
      wpr = powf(wsr, gmr);
      wpw = powf(wsw, gmw);
      float sr = wpr, sw = wpw;
      wred_sum2(sr, sw);
      if (lane == 0) { s.red[0][wave] = sr; s.red[1][wave] = sw; }
    }
    __syncthreads();                                   // bar 8

    // ---- P9: normalize -> new weight states ----
    {
      float spr = s.red[0][wb0] + s.red[0][wb0+1] + s.red[0][wb0+2] + s.red[0][wb0+3];
      float spw = s.red[1][wb0] + s.red[1][wb0+1] + s.red[1][wb0+2] + s.red[1][wb0+3];
      s.wr[g2][n2] = wpr / (spr + EPSF);
      s.ww[g2][n2] = wpw / (spw + EPSF);
    }
    __syncthreads();                                   // bar 9

    // ---- P10: R partials = wr . M (pre-write M), 8 chunks x 32 m ----
    {
      const int chunk = n2 >> 5;
      const int m     = n2 & 31;
      const int nb    = chunk * 32;
      float acc = 0.0f;
      #pragma unroll 4
      for (int nn = 0; nn < 32; ++nn) {
        const int n = nb + nn;
        acc = fmaf(s.wr[g2][n], s.M[g2][n][m], acc);
      }
      s.rpart[g2][chunk][m] = acc;
    }
    __syncthreads();                                   // bar 10

    // ---- P11: R finalize + memory write M = M*(1-ww*E) + ww*A ----
    if (n2 < MU) {
      float r = 0.0f;
      #pragma unroll
      for (int c = 0; c < 8; ++c) r += s.rpart[g2][c][n2];
      s.R[g2][n2] = r;
    }
    {
      const float wwn = s.ww[g2][n2];
      float* Mr = &s.M[g2][n2][0];
      #pragma unroll
      for (int m = 0; m < MU; ++m) {
        Mr[m] = Mr[m] * (1.0f - wwn*s.E[g2][m]) + wwn*s.A[g2][m];
      }
    }
    __syncthreads();                                   // bar 11

    // ---- P12: output Y = clip([R|h]@oW + b) ; next-step xcat ----
    {
      const int o = n2 >> 5;   // 0..7
      const int l = n2 & 31;
      float acc = 0.0f;
      #pragma unroll
      for (int ss = 0; ss < 9; ++ss) {
        const int j = l + 32*ss;     // covers 0..287 exactly
        float v = (j < 32) ? s.R[g2][j] : s.h[g2][j - 32];
        acc = fmaf(v, oW[j*8 + o], acc);
      }
      #pragma unroll
      for (int m = 16; m >= 1; m >>= 1) acc += __shfl_xor(acc, m, 64);
      if (l == 0) {
        float y = acc + ob[o];
        y = fminf(fmaxf(y, -20.0f), 20.0f);
        Y[((bB + g2)*TSTEPS + t)*8 + o] = y;
      }
      if (n2 >= 8 && n2 < 40) {
        s.xcat[g2][n2] = s.R[g2][n2 - 8];
      } else if (n2 < 8 && t + 1 < TSTEPS) {
        s.xcat[g2][n2] = X[((bB + g2)*TSTEPS + (t+1))*8 + n2];
      }
    }
    __syncthreads();                                   // bar 12
  }
}

extern "C" void kernel_launch(void* const* d_in, const int* in_sizes, int n_in,
                              void* d_out, int out_size, void* d_ws, size_t ws_size,
                              hipStream_t stream)
{
  const float* X     = (const float*)d_in[0];
  const float* Wk    = (const float*)d_in[1];
  const float* Wr    = (const float*)d_in[2];
  const float* Lb    = (const float*)d_in[3];
  const float* rW    = (const float*)d_in[4];
  const float* rb    = (const float*)d_in[5];
  const float* wW    = (const float*)d_in[6];
  const float* wb    = (const float*)d_in[7];
  const float* oW    = (const float*)d_in[8];
  const float* ob    = (const float*)d_in[9];
  const float* rInit = (const float*)d_in[10];
  const float* wrI   = (const float*)d_in[11];
  const float* wwI   = (const float*)d_in[12];
  float* Y = (float*)d_out;

  hipLaunchKernelGGL(ntm_fused, dim3(256), dim3(512), 0, stream,
                     X, Wk, Wr, Lb, rW, rb, wW, wb, oW, ob, rInit, wrI, wwI, Y);
}